// Round 1
// 122.623 us; speedup vs baseline: 1.0060x; 1.0060x over previous
//
#include <hip/hip_runtime.h>

typedef __fp16 f16;
typedef __fp16 f16x8 __attribute__((ext_vector_type(8)));
typedef __fp16 f16x4 __attribute__((ext_vector_type(4)));
typedef __fp16 f16x2 __attribute__((ext_vector_type(2)));
typedef float f32x4 __attribute__((ext_vector_type(4)));
typedef float f32x16 __attribute__((ext_vector_type(16)));

#define D_MODEL 1024
#define SEQ 2048
#define NH 16
#define MTOT 4096  // B*S

typedef const __attribute__((address_space(1))) unsigned int* gp1_t;
typedef __attribute__((address_space(3))) unsigned int* lp3_t;

__device__ __forceinline__ void gload_lds16(const void* g, void* l) {
  __builtin_amdgcn_global_load_lds((gp1_t)g, (lp3_t)l, 16, 0, 0);
}

// Z-row r' -> AO superrow j (the reference's transpose/view bug, closed form)
__device__ __forceinline__ int permrow(int r) {
  int bp = r >> 11, u = (r >> 7) & 15, t = r & 127;
  int g16 = (bp << 4) | u;
  return ((((g16 & 1) << 4) | (g16 >> 1)) << 7) + t;  // (b*16+h)*128 + t
}

__device__ __forceinline__ unsigned int pkrtz(float a, float b) {
  union { f16x2 h; unsigned int u; } z;
  z.h = __builtin_amdgcn_cvt_pkrtz(a, b);
  return z.u;
}

// ---------------- merged converts: qkv fp32->f16 (blocks 0..6143), wT (blocks 6144..7167) ----------------
__global__ __launch_bounds__(256) void cvt_all(const float* __restrict__ q,
                                               const float* __restrict__ k,
                                               const float* __restrict__ v,
                                               const float* __restrict__ wq,
                                               const float* __restrict__ wk,
                                               const float* __restrict__ wv,
                                               const float* __restrict__ wo,
                                               f16* __restrict__ qkv16,
                                               f16* __restrict__ wT) {
  __shared__ float tl[64][65];
  int bid = blockIdx.x, tid = threadIdx.x;
  if (bid < 6144) {
    int i = bid * 256 + tid;
    const int NT = (MTOT * D_MODEL) / 8;
    const float* src;
    int t;
    if (i < NT) { src = q; t = i; }
    else if (i < 2 * NT) { src = k; t = i - NT; }
    else { src = v; t = i - 2 * NT; }
    const float4* s4 = (const float4*)src;
    float4 a = s4[2 * t], b = s4[2 * t + 1];
    f16x8 h;
    h[0] = (f16)a.x; h[1] = (f16)a.y; h[2] = (f16)a.z; h[3] = (f16)a.w;
    h[4] = (f16)b.x; h[5] = (f16)b.y; h[6] = (f16)b.z; h[7] = (f16)b.w;
    *(f16x8*)(qkv16 + (size_t)i * 8) = h;
  } else {
    int bb = bid - 6144;
    int mat = bb >> 8, tile = bb & 255;
    int tk = (tile >> 4) << 6, tn = (tile & 15) << 6;
    const float* W = mat == 0 ? wq : mat == 1 ? wk : mat == 2 ? wv : wo;
    int rr = tid >> 4, c4 = (tid & 15) << 2;
#pragma unroll
    for (int it = 0; it < 4; ++it) {
      const float* p = W + (size_t)(tk + it * 16 + rr) * D_MODEL + tn + c4;
      float4 val = *(const float4*)p;
      tl[it * 16 + rr][c4 + 0] = val.x;
      tl[it * 16 + rr][c4 + 1] = val.y;
      tl[it * 16 + rr][c4 + 2] = val.z;
      tl[it * 16 + rr][c4 + 3] = val.w;
    }
    __syncthreads();
    int n = tid & 63, kseg = (tid >> 6) << 4;
    f16x8 lo, hi;
#pragma unroll
    for (int j = 0; j < 8; ++j) lo[j] = (f16)tl[kseg + j][n];
#pragma unroll
    for (int j = 0; j < 8; ++j) hi[j] = (f16)tl[kseg + 8 + j][n];
    f16* d = wT + (size_t)mat * (D_MODEL * D_MODEL) + (size_t)(tn + n) * D_MODEL + tk + kseg;
    *(f16x8*)d = lo;
    *(f16x8*)(d + 8) = hi;
  }
}

// ---------------- fused QKV projection GEMM: 128x128 tiles, grid (32,8,3) ----------------
__global__ __launch_bounds__(256, 2) void gemm_qkv(const f16* __restrict__ q16,
                                                   const f16* __restrict__ k16,
                                                   const f16* __restrict__ v16,
                                                   const f16* __restrict__ wT,
                                                   const float* __restrict__ bq,
                                                   const float* __restrict__ bk,
                                                   const float* __restrict__ bv,
                                                   f16* __restrict__ Q16,
                                                   f16* __restrict__ K16,
                                                   f16* __restrict__ VT16) {
  const int K = D_MODEL, N = D_MODEL;
  const size_t WEL = (size_t)D_MODEL * D_MODEL;
  int z = blockIdx.z;
  const f16* A = z == 0 ? q16 : z == 1 ? k16 : v16;
  const f16* BT = wT + (size_t)z * WEL;
  const float* bias = z == 0 ? bq : z == 1 ? bk : bv;

  __shared__ f16 As[128 * 64];
  __shared__ f16 Bs[128 * 64];
  int tid = threadIdx.x;
  int w = tid >> 6, lane = tid & 63;
  int g = lane >> 4, c = lane & 15;
  int wr = w >> 1, wc = w & 1;
  int m0 = blockIdx.x * 128, n0 = blockIdx.y * 128;
  f32x4 acc[4][4] = {};

  for (int kt = 0; kt < K; kt += 64) {
#pragma unroll
    for (int i = 0; i < 4; ++i) {
      int seg = w * 4 + i;
      int p = seg * 1024 + lane * 16;
      int row = p >> 7;
      int colb = (p & 127) ^ ((row & 7) << 4);
      int ae = kt + (colb >> 1);
      gload_lds16(A + (size_t)(m0 + row) * K + ae, &As[seg * 512]);
      gload_lds16(BT + (size_t)(n0 + row) * K + ae, &Bs[seg * 512]);
    }
    __syncthreads();
    f16x8 af[4][2], bf[4][2];
#pragma unroll
    for (int m = 0; m < 4; ++m) {
#pragma unroll
      for (int kk = 0; kk < 2; ++kk) {
        int row = wr * 64 + m * 16 + c;
        int tb = (row * 128 + kk * 64 + g * 16) ^ ((row & 7) << 4);
        af[m][kk] = *(const f16x8*)((const char*)As + tb);
      }
    }
#pragma unroll
    for (int n = 0; n < 4; ++n) {
#pragma unroll
      for (int kk = 0; kk < 2; ++kk) {
        int row = wc * 64 + n * 16 + c;
        int tb = (row * 128 + kk * 64 + g * 16) ^ ((row & 7) << 4);
        bf[n][kk] = *(const f16x8*)((const char*)Bs + tb);
      }
    }
    __builtin_amdgcn_s_setprio(1);
#pragma unroll
    for (int m = 0; m < 4; ++m)
#pragma unroll
      for (int n = 0; n < 4; ++n)
#pragma unroll
        for (int kk = 0; kk < 2; ++kk)
          acc[m][n] = __builtin_amdgcn_mfma_f32_16x16x32_f16(af[m][kk], bf[n][kk], acc[m][n], 0, 0, 0);
    __builtin_amdgcn_s_setprio(0);
    __syncthreads();
  }

  int rb = m0 + wr * 64;
  int cb = n0 + wc * 64;
  if (z < 2) {
    f16* O = z == 0 ? Q16 : K16;
#pragma unroll
    for (int m = 0; m < 4; ++m) {
      int row0 = rb + m * 16 + 4 * g;
#pragma unroll
      for (int n = 0; n < 4; ++n) {
        int col = cb + n * 16 + c;
        float bv2 = bias[col];
#pragma unroll
        for (int r = 0; r < 4; ++r) O[(size_t)(row0 + r) * N + col] = (f16)(acc[m][n][r] + bv2);
      }
    }
  } else {
    f16* O = VT16;
#pragma unroll
    for (int m = 0; m < 4; ++m) {
      int s0f = rb + m * 16 + 4 * g;
      int bb = s0f >> 11, s = s0f & (SEQ - 1);
#pragma unroll
      for (int n = 0; n < 4; ++n) {
        int col = cb + n * 16 + c;
        float bv2 = bias[col];
        f16x4 hv;
#pragma unroll
        for (int r = 0; r < 4; ++r) hv[r] = (f16)(acc[m][n][r] + bv2);
        *(f16x4*)(O + ((size_t)(bb * NH + (col >> 6)) * 64 + (col & 63)) * SEQ + s) = hv;
      }
    }
  }
}

// ---------------- O-projection GEMM: 64x128 tiles, permuted A rows, f32 out ----------------
__global__ __launch_bounds__(256, 2) void gemm_out(const f16* __restrict__ A,
                                                   const f16* __restrict__ BT,
                                                   const float* __restrict__ bias,
                                                   float* __restrict__ O) {
  const int K = D_MODEL, N = D_MODEL;
  __shared__ f16 As[64 * 64];
  __shared__ f16 Bs[128 * 64];
  int tid = threadIdx.x;
  int w = tid >> 6, lane = tid & 63;
  int g = lane >> 4, c = lane & 15;
  int wr = w >> 1, wc = w & 1;
  int m0 = blockIdx.x * 64, n0 = blockIdx.y * 128;
  f32x4 acc[2][4] = {};

  for (int kt = 0; kt < K; kt += 64) {
#pragma unroll
    for (int i = 0; i < 2; ++i) {
      int seg = w * 2 + i;
      int p = seg * 1024 + lane * 16;
      int row = p >> 7;
      int colb = (p & 127) ^ ((row & 7) << 4);
      int ae = kt + (colb >> 1);
      gload_lds16(A + (size_t)permrow(m0 + row) * K + ae, &As[seg * 512]);
    }
#pragma unroll
    for (int i = 0; i < 4; ++i) {
      int seg = w * 4 + i;
      int p = seg * 1024 + lane * 16;
      int row = p >> 7;
      int colb = (p & 127) ^ ((row & 7) << 4);
      int ae = kt + (colb >> 1);
      gload_lds16(BT + (size_t)(n0 + row) * K + ae, &Bs[seg * 512]);
    }
    __syncthreads();
    f16x8 af[2][2], bf[4][2];
#pragma unroll
    for (int m = 0; m < 2; ++m) {
#pragma unroll
      for (int kk = 0; kk < 2; ++kk) {
        int row = wr * 32 + m * 16 + c;
        int tb = (row * 128 + kk * 64 + g * 16) ^ ((row & 7) << 4);
        af[m][kk] = *(const f16x8*)((const char*)As + tb);
      }
    }
#pragma unroll
    for (int n = 0; n < 4; ++n) {
#pragma unroll
      for (int kk = 0; kk < 2; ++kk) {
        int row = wc * 64 + n * 16 + c;
        int tb = (row * 128 + kk * 64 + g * 16) ^ ((row & 7) << 4);
        bf[n][kk] = *(const f16x8*)((const char*)Bs + tb);
      }
    }
    __builtin_amdgcn_s_setprio(1);
#pragma unroll
    for (int m = 0; m < 2; ++m)
#pragma unroll
      for (int n = 0; n < 4; ++n)
#pragma unroll
        for (int kk = 0; kk < 2; ++kk)
          acc[m][n] = __builtin_amdgcn_mfma_f32_16x16x32_f16(af[m][kk], bf[n][kk], acc[m][n], 0, 0, 0);
    __builtin_amdgcn_s_setprio(0);
    __syncthreads();
  }

  int rb = m0 + wr * 32;
  int cb = n0 + wc * 64;
#pragma unroll
  for (int m = 0; m < 2; ++m) {
    int row0 = rb + m * 16 + 4 * g;
#pragma unroll
    for (int n = 0; n < 4; ++n) {
      int col = cb + n * 16 + c;
      float bv = bias[col];
#pragma unroll
      for (int r = 0; r < 4; ++r) O[(size_t)(row0 + r) * N + col] = acc[m][n][r] + bv;
    }
  }
}

// ---------------- causal flash attention v6: swapped 32x32 MFMA, in-register softmax ----------------
// Block = 2 waves x 32 q-rows = 64 rows; grid 1024 = 32 chunk-slots x 32 bh (same
// balanced slot->chunk map as v5: every CU gets blocks {g,15-g,16+g,31-g} = 66 tiles).
// QK^T computed swapped (mfma(K,Q) -> S^T, col=q) so each lane owns one q-row:
// softmax m/l/corr are per-lane scalars; PV computed as O^T = V^T * P^T (col=q again),
// with P built in-register via v_cvt_pkrtz + v_permlane32_swap (no P LDS round-trip).
#define THR2 11.5f  // defer-max threshold, log2 domain
__global__ __launch_bounds__(128, 2) void attn_kernel(const f16* __restrict__ Q,
                                                      const f16* __restrict__ K,
                                                      const f16* __restrict__ VT,
                                                      f16* __restrict__ AO) {
  __shared__ __attribute__((aligned(16))) f16 Ksh[2][64 * 64];  // 16 KB
  __shared__ __attribute__((aligned(16))) f16 Vsh[2][64 * 64];  // 16 KB
  int tid = threadIdx.x;
  int w = tid >> 6, lane = tid & 63;
  int c = lane & 31, hi = lane >> 5;
  int blk = blockIdx.x;
  int bh = blk & 31;               // low bits -> head pinned per XCD
  int uu = blk >> 5;               // chunk slot 0..31
  int grp = uu & 7, pos = uu >> 3;
  int cb = pos == 0 ? grp : pos == 1 ? 15 - grp : pos == 2 ? 16 + grp : 31 - grp;
  int b = bh >> 4, h = bh & 15;
  int q0 = cb * 64 + w * 32;
  const int NT = cb + 1;
  const size_t brow = (size_t)b * SEQ;
  const int hcol = h * 64;

  // staging geometry: wave stages rows w*32 + j*8 + (lane>>3), XOR-swizzled source cols
  int sr = lane >> 3;
  int seo = ((lane & 7) ^ sr) << 3;
  const f16* Kgb = K + (size_t)(brow + w * 32 + sr) * D_MODEL + hcol + seo;
  const f16* Vgb = VT + ((size_t)bh * 64 + w * 32 + sr) * SEQ + seo;

  // Q B-fragments (col=q-row=c, k = 16*kk + 8*hi + j), pre-scaled by log2e
  const f16 LOG2E = (f16)1.44269504f;
  f16x8 qf[4];
  const f16* Qp = Q + (size_t)(brow + q0 + c) * D_MODEL + hcol + 8 * hi;
#pragma unroll
  for (int kk = 0; kk < 4; ++kk) {
    qf[kk] = *(const f16x8*)(Qp + 16 * kk);
#pragma unroll
    for (int j = 0; j < 8; ++j) qf[kk][j] = (f16)(qf[kk][j] * LOG2E);
  }

  float m_st = -1e30f, l_st = 0.f;
  f32x16 o0 = {}, o1 = {};  // O^T accumulators, d-tiles 0..31 / 32..63; col=q per lane

  // prologue: stage tile 0 into buf 0
#pragma unroll
  for (int j = 0; j < 4; ++j) {
    gload_lds16(Kgb + (size_t)(j * 8) * D_MODEL, &Ksh[0][(w * 32 + j * 8) * 64]);
    gload_lds16(Vgb + (size_t)(j * 8) * SEQ, &Vsh[0][(w * 32 + j * 8) * 64]);
  }
  __syncthreads();

  int rsw = (c & 7) << 4;
  int cur = 0;
  for (int t = 0; t < NT; ++t) {
    if (t + 1 < NT) {
      int kv1 = (t + 1) * 64;
      int nx = cur ^ 1;
#pragma unroll
      for (int j = 0; j < 4; ++j) {
        gload_lds16(Kgb + (size_t)(kv1 + j * 8) * D_MODEL, &Ksh[nx][(w * 32 + j * 8) * 64]);
        gload_lds16(Vgb + (size_t)(j * 8) * SEQ + kv1, &Vsh[nx][(w * 32 + j * 8) * 64]);
      }
    }
    const char* Kb = (const char*)&Ksh[cur][0];
    const char* Vb = (const char*)&Vsh[cur][0];
    // ---- QK^T swapped: S^T[kv][q] = K . Q^T ----
    f16x8 kf[2][4];
#pragma unroll
    for (int ks = 0; ks < 2; ++ks)
#pragma unroll
      for (int kk = 0; kk < 4; ++kk)
        kf[ks][kk] = *(const f16x8*)(Kb + (((ks * 32 + c) * 128 + 32 * kk + 16 * hi) ^ rsw));
    f32x16 s0 = {}, s1 = {};
    __builtin_amdgcn_s_setprio(1);
#pragma unroll
    for (int kk = 0; kk < 4; ++kk) {
      s0 = __builtin_amdgcn_mfma_f32_32x32x16_f16(kf[0][kk], qf[kk], s0, 0, 0, 0);
      s1 = __builtin_amdgcn_mfma_f32_32x32x16_f16(kf[1][kk], qf[kk], s1, 0, 0, 0);
    }
    __builtin_amdgcn_s_setprio(0);
    // ---- causal mask (diagonal tile only); kv = 64t + 32ks + (r&3)+8(r>>2)+4hi ----
    if (t == NT - 1) {
      int q = q0 + c;
      int kvb = t * 64 + 4 * hi;
#pragma unroll
      for (int r = 0; r < 16; ++r) {
        int kv = kvb + (r & 3) + 8 * (r >> 2);
        if (kv > q) s0[r] = -1e30f;
        if (kv + 32 > q) s1[r] = -1e30f;
      }
    }
    // ---- online softmax: each lane holds 32 scores of ONE q-row (other half at lane^32) ----
    float t8[8];
#pragma unroll
    for (int r = 0; r < 8; ++r)
      t8[r] = fmaxf(fmaxf(s0[r], s0[r + 8]), fmaxf(s1[r], s1[r + 8]));
    float pm = fmaxf(fmaxf(fmaxf(t8[0], t8[1]), fmaxf(t8[2], t8[3])),
                     fmaxf(fmaxf(t8[4], t8[5]), fmaxf(t8[6], t8[7])));
    float mx = fmaxf(pm, __shfl_xor(pm, 32));
    if (__any(mx > m_st + THR2)) {
      float mnew = fmaxf(m_st, mx);
      float corr = __builtin_amdgcn_exp2f(m_st - mnew);
      l_st *= corr;
#pragma unroll
      for (int r = 0; r < 16; ++r) { o0[r] *= corr; o1[r] *= corr; }
      m_st = mnew;
    }
    float lacc = 0.f;
#pragma unroll
    for (int r = 0; r < 16; ++r) {
      float p0 = __builtin_amdgcn_exp2f(s0[r] - m_st);  // <= 2^11.5, f16-safe
      float p1 = __builtin_amdgcn_exp2f(s1[r] - m_st);
      s0[r] = p0; s1[r] = p1;
      lacc += p0 + p1;
    }
    l_st += lacc;
    // ---- P -> PV B-fragments in-register (cvt_pkrtz pairs + permlane32 hi/lo swap) ----
    // B-frag[kk] lane(c,hi): kv = 16kk + 8hi + jj. Source reg = (jj&3) + 8(kk&1) + 4hi
    // at lane (c, jj>>2). swap(La,Lb) yields slot0=La' (own/partner-lo), slot2=Lb'.
    union PU { unsigned int u[4]; f16x8 v; };
    PU pu[4];
#pragma unroll
    for (int kk = 0; kk < 4; ++kk) {
      int rb = 8 * (kk & 1);
      unsigned int la0, la1, lb0, lb1;
      if (kk < 2) {
        la0 = pkrtz(s0[rb + 0], s0[rb + 1]);
        la1 = pkrtz(s0[rb + 2], s0[rb + 3]);
        lb0 = pkrtz(s0[rb + 4], s0[rb + 5]);
        lb1 = pkrtz(s0[rb + 6], s0[rb + 7]);
      } else {
        la0 = pkrtz(s1[rb + 0], s1[rb + 1]);
        la1 = pkrtz(s1[rb + 2], s1[rb + 3]);
        lb0 = pkrtz(s1[rb + 4], s1[rb + 5]);
        lb1 = pkrtz(s1[rb + 6], s1[rb + 7]);
      }
      asm("v_permlane32_swap_b32 %0, %1" : "+v"(la0), "+v"(lb0));
      asm("v_permlane32_swap_b32 %0, %1" : "+v"(la1), "+v"(lb1));
      pu[kk].u[0] = la0; pu[kk].u[1] = la1; pu[kk].u[2] = lb0; pu[kk].u[3] = lb1;
    }
    // ---- PV: O^T[d][q] += V^T[d][kv] * P^T[kv][q] ----
    f16x8 vf[2][4];
#pragma unroll
    for (int dt = 0; dt < 2; ++dt)
#pragma unroll
      for (int kk = 0; kk < 4; ++kk)
        vf[dt][kk] = *(const f16x8*)(Vb + (((dt * 32 + c) * 128 + 32 * kk + 16 * hi) ^ rsw));
    __builtin_amdgcn_s_setprio(1);
#pragma unroll
    for (int kk = 0; kk < 4; ++kk) {
      o0 = __builtin_amdgcn_mfma_f32_32x32x16_f16(vf[0][kk], pu[kk].v, o0, 0, 0, 0);
      o1 = __builtin_amdgcn_mfma_f32_32x32x16_f16(vf[1][kk], pu[kk].v, o1, 0, 0, 0);
    }
    __builtin_amdgcn_s_setprio(0);
    __syncthreads();
    cur ^= 1;
  }

  // ---- finalize: combine hi/lo row-sum halves, normalize, write AO[bh][s][64] ----
  float lt = l_st + __shfl_xor(l_st, 32);
  float linv = 1.0f / lt;
  f16* aoq = AO + ((size_t)bh * SEQ + q0 + c) * 64 + 4 * hi;
#pragma unroll
  for (int rq = 0; rq < 4; ++rq) {
    f16x4 h0, h1;
#pragma unroll
    for (int r = 0; r < 4; ++r) {
      h0[r] = (f16)(o0[4 * rq + r] * linv);
      h1[r] = (f16)(o1[4 * rq + r] * linv);
    }
    *(f16x4*)(aoq + 8 * rq) = h0;
    *(f16x4*)(aoq + 32 + 8 * rq) = h1;
  }
}

extern "C" void kernel_launch(void* const* d_in, const int* in_sizes, int n_in,
                              void* d_out, int out_size, void* d_ws, size_t ws_size,
                              hipStream_t stream) {
  const float* q  = (const float*)d_in[0];
  const float* k  = (const float*)d_in[1];
  const float* v  = (const float*)d_in[2];
  const float* wq = (const float*)d_in[3];
  const float* bq = (const float*)d_in[4];
  const float* wk = (const float*)d_in[5];
  const float* bk = (const float*)d_in[6];
  const float* wv = (const float*)d_in[7];
  const float* bv = (const float*)d_in[8];
  const float* wo = (const float*)d_in[9];
  const float* bo = (const float*)d_in[10];

  const size_t TEN = (size_t)MTOT * D_MODEL;
  const size_t WEL = (size_t)D_MODEL * D_MODEL;
  f16* ws  = (f16*)d_ws;
  f16* q16 = ws;
  f16* k16 = q16 + TEN;
  f16* v16 = k16 + TEN;
  f16* wT  = v16 + TEN;
  f16* Q16 = wT + 4 * WEL;
  f16* K16 = Q16 + TEN;
  f16* VT16 = K16 + TEN;
  f16* AO  = q16;  // alias: q16 dead after QKV projection

  cvt_all<<<7168, 256, 0, stream>>>(q, k, v, wq, wk, wv, wo, q16, wT);
  gemm_qkv<<<dim3(32, 8, 3), 256, 0, stream>>>(q16, k16, v16, wT, bq, bk, bv, Q16, K16, VT16);
  attn_kernel<<<1024, 128, 0, stream>>>(Q16, K16, VT16, AO);
  gemm_out<<<dim3(64, 8), 256, 0, stream>>>(AO, wT + 3 * WEL, bo, (float*)d_out);
}

// Round 2
// 110.771 us; speedup vs baseline: 1.1136x; 1.1070x over previous
//
#include <hip/hip_runtime.h>

typedef __fp16 f16;
typedef __fp16 f16x8 __attribute__((ext_vector_type(8)));
typedef __fp16 f16x4 __attribute__((ext_vector_type(4)));
typedef __fp16 f16x2 __attribute__((ext_vector_type(2)));
typedef float f32x4 __attribute__((ext_vector_type(4)));
typedef float f32x16 __attribute__((ext_vector_type(16)));

#define D_MODEL 1024
#define SEQ 2048
#define NH 16
#define MTOT 4096  // B*S

typedef const __attribute__((address_space(1))) unsigned int* gp1_t;
typedef __attribute__((address_space(3))) unsigned int* lp3_t;

__device__ __forceinline__ void gload_lds16(const void* g, void* l) {
  __builtin_amdgcn_global_load_lds((gp1_t)g, (lp3_t)l, 16, 0, 0);
}

// Z-row r' -> AO superrow j (the reference's transpose/view bug, closed form)
__device__ __forceinline__ int permrow(int r) {
  int bp = r >> 11, u = (r >> 7) & 15, t = r & 127;
  int g16 = (bp << 4) | u;
  return ((((g16 & 1) << 4) | (g16 >> 1)) << 7) + t;  // (b*16+h)*128 + t
}

__device__ __forceinline__ unsigned int pkrtz(float a, float b) {
  union { f16x2 h; unsigned int u; } z;
  z.h = __builtin_amdgcn_cvt_pkrtz(a, b);
  return z.u;
}

// ---------------- merged converts: qkv fp32->f16 (blocks 0..6143), wT (blocks 6144..7167) ----------------
__global__ __launch_bounds__(256) void cvt_all(const float* __restrict__ q,
                                               const float* __restrict__ k,
                                               const float* __restrict__ v,
                                               const float* __restrict__ wq,
                                               const float* __restrict__ wk,
                                               const float* __restrict__ wv,
                                               const float* __restrict__ wo,
                                               f16* __restrict__ qkv16,
                                               f16* __restrict__ wT) {
  __shared__ float tl[64][65];
  int bid = blockIdx.x, tid = threadIdx.x;
  if (bid < 6144) {
    int i = bid * 256 + tid;
    const int NT = (MTOT * D_MODEL) / 8;
    const float* src;
    int t;
    if (i < NT) { src = q; t = i; }
    else if (i < 2 * NT) { src = k; t = i - NT; }
    else { src = v; t = i - 2 * NT; }
    const float4* s4 = (const float4*)src;
    float4 a = s4[2 * t], b = s4[2 * t + 1];
    f16x8 h;
    h[0] = (f16)a.x; h[1] = (f16)a.y; h[2] = (f16)a.z; h[3] = (f16)a.w;
    h[4] = (f16)b.x; h[5] = (f16)b.y; h[6] = (f16)b.z; h[7] = (f16)b.w;
    *(f16x8*)(qkv16 + (size_t)i * 8) = h;
  } else {
    int bb = bid - 6144;
    int mat = bb >> 8, tile = bb & 255;
    int tk = (tile >> 4) << 6, tn = (tile & 15) << 6;
    const float* W = mat == 0 ? wq : mat == 1 ? wk : mat == 2 ? wv : wo;
    int rr = tid >> 4, c4 = (tid & 15) << 2;
#pragma unroll
    for (int it = 0; it < 4; ++it) {
      const float* p = W + (size_t)(tk + it * 16 + rr) * D_MODEL + tn + c4;
      float4 val = *(const float4*)p;
      tl[it * 16 + rr][c4 + 0] = val.x;
      tl[it * 16 + rr][c4 + 1] = val.y;
      tl[it * 16 + rr][c4 + 2] = val.z;
      tl[it * 16 + rr][c4 + 3] = val.w;
    }
    __syncthreads();
    int n = tid & 63, kseg = (tid >> 6) << 4;
    f16x8 lo, hi;
#pragma unroll
    for (int j = 0; j < 8; ++j) lo[j] = (f16)tl[kseg + j][n];
#pragma unroll
    for (int j = 0; j < 8; ++j) hi[j] = (f16)tl[kseg + 8 + j][n];
    f16* d = wT + (size_t)mat * (D_MODEL * D_MODEL) + (size_t)(tn + n) * D_MODEL + tk + kseg;
    *(f16x8*)d = lo;
    *(f16x8*)(d + 8) = hi;
  }
}

// ---------------- fused QKV projection GEMM: 128x128 tiles, grid (32,8,3) ----------------
__global__ __launch_bounds__(256, 2) void gemm_qkv(const f16* __restrict__ q16,
                                                   const f16* __restrict__ k16,
                                                   const f16* __restrict__ v16,
                                                   const f16* __restrict__ wT,
                                                   const float* __restrict__ bq,
                                                   const float* __restrict__ bk,
                                                   const float* __restrict__ bv,
                                                   f16* __restrict__ Q16,
                                                   f16* __restrict__ K16,
                                                   f16* __restrict__ VT16) {
  const int K = D_MODEL, N = D_MODEL;
  const size_t WEL = (size_t)D_MODEL * D_MODEL;
  int z = blockIdx.z;
  const f16* A = z == 0 ? q16 : z == 1 ? k16 : v16;
  const f16* BT = wT + (size_t)z * WEL;
  const float* bias = z == 0 ? bq : z == 1 ? bk : bv;

  __shared__ f16 As[128 * 64];
  __shared__ f16 Bs[128 * 64];
  int tid = threadIdx.x;
  int w = tid >> 6, lane = tid & 63;
  int g = lane >> 4, c = lane & 15;
  int wr = w >> 1, wc = w & 1;
  int m0 = blockIdx.x * 128, n0 = blockIdx.y * 128;
  f32x4 acc[4][4] = {};

  for (int kt = 0; kt < K; kt += 64) {
#pragma unroll
    for (int i = 0; i < 4; ++i) {
      int seg = w * 4 + i;
      int p = seg * 1024 + lane * 16;
      int row = p >> 7;
      int colb = (p & 127) ^ ((row & 7) << 4);
      int ae = kt + (colb >> 1);
      gload_lds16(A + (size_t)(m0 + row) * K + ae, &As[seg * 512]);
      gload_lds16(BT + (size_t)(n0 + row) * K + ae, &Bs[seg * 512]);
    }
    __syncthreads();
    f16x8 af[4][2], bf[4][2];
#pragma unroll
    for (int m = 0; m < 4; ++m) {
#pragma unroll
      for (int kk = 0; kk < 2; ++kk) {
        int row = wr * 64 + m * 16 + c;
        int tb = (row * 128 + kk * 64 + g * 16) ^ ((row & 7) << 4);
        af[m][kk] = *(const f16x8*)((const char*)As + tb);
      }
    }
#pragma unroll
    for (int n = 0; n < 4; ++n) {
#pragma unroll
      for (int kk = 0; kk < 2; ++kk) {
        int row = wc * 64 + n * 16 + c;
        int tb = (row * 128 + kk * 64 + g * 16) ^ ((row & 7) << 4);
        bf[n][kk] = *(const f16x8*)((const char*)Bs + tb);
      }
    }
    __builtin_amdgcn_s_setprio(1);
#pragma unroll
    for (int m = 0; m < 4; ++m)
#pragma unroll
      for (int n = 0; n < 4; ++n)
#pragma unroll
        for (int kk = 0; kk < 2; ++kk)
          acc[m][n] = __builtin_amdgcn_mfma_f32_16x16x32_f16(af[m][kk], bf[n][kk], acc[m][n], 0, 0, 0);
    __builtin_amdgcn_s_setprio(0);
    __syncthreads();
  }

  int rb = m0 + wr * 64;
  int cb = n0 + wc * 64;
  if (z < 2) {
    f16* O = z == 0 ? Q16 : K16;
#pragma unroll
    for (int m = 0; m < 4; ++m) {
      int row0 = rb + m * 16 + 4 * g;
#pragma unroll
      for (int n = 0; n < 4; ++n) {
        int col = cb + n * 16 + c;
        float bv2 = bias[col];
#pragma unroll
        for (int r = 0; r < 4; ++r) O[(size_t)(row0 + r) * N + col] = (f16)(acc[m][n][r] + bv2);
      }
    }
  } else {
    f16* O = VT16;
#pragma unroll
    for (int m = 0; m < 4; ++m) {
      int s0f = rb + m * 16 + 4 * g;
      int bb = s0f >> 11, s = s0f & (SEQ - 1);
#pragma unroll
      for (int n = 0; n < 4; ++n) {
        int col = cb + n * 16 + c;
        float bv2 = bias[col];
        f16x4 hv;
#pragma unroll
        for (int r = 0; r < 4; ++r) hv[r] = (f16)(acc[m][n][r] + bv2);
        *(f16x4*)(O + ((size_t)(bb * NH + (col >> 6)) * 64 + (col & 63)) * SEQ + s) = hv;
      }
    }
  }
}

// ---------------- O-projection GEMM: 64x128 tiles, permuted A rows, f32 out ----------------
__global__ __launch_bounds__(256, 2) void gemm_out(const f16* __restrict__ A,
                                                   const f16* __restrict__ BT,
                                                   const float* __restrict__ bias,
                                                   float* __restrict__ O) {
  const int K = D_MODEL, N = D_MODEL;
  __shared__ f16 As[64 * 64];
  __shared__ f16 Bs[128 * 64];
  int tid = threadIdx.x;
  int w = tid >> 6, lane = tid & 63;
  int g = lane >> 4, c = lane & 15;
  int wr = w >> 1, wc = w & 1;
  int m0 = blockIdx.x * 64, n0 = blockIdx.y * 128;
  f32x4 acc[2][4] = {};

  for (int kt = 0; kt < K; kt += 64) {
#pragma unroll
    for (int i = 0; i < 2; ++i) {
      int seg = w * 2 + i;
      int p = seg * 1024 + lane * 16;
      int row = p >> 7;
      int colb = (p & 127) ^ ((row & 7) << 4);
      int ae = kt + (colb >> 1);
      gload_lds16(A + (size_t)permrow(m0 + row) * K + ae, &As[seg * 512]);
    }
#pragma unroll
    for (int i = 0; i < 4; ++i) {
      int seg = w * 4 + i;
      int p = seg * 1024 + lane * 16;
      int row = p >> 7;
      int colb = (p & 127) ^ ((row & 7) << 4);
      int ae = kt + (colb >> 1);
      gload_lds16(BT + (size_t)(n0 + row) * K + ae, &Bs[seg * 512]);
    }
    __syncthreads();
    f16x8 af[2][2], bf[4][2];
#pragma unroll
    for (int m = 0; m < 2; ++m) {
#pragma unroll
      for (int kk = 0; kk < 2; ++kk) {
        int row = wr * 32 + m * 16 + c;
        int tb = (row * 128 + kk * 64 + g * 16) ^ ((row & 7) << 4);
        af[m][kk] = *(const f16x8*)((const char*)As + tb);
      }
    }
#pragma unroll
    for (int n = 0; n < 4; ++n) {
#pragma unroll
      for (int kk = 0; kk < 2; ++kk) {
        int row = wc * 64 + n * 16 + c;
        int tb = (row * 128 + kk * 64 + g * 16) ^ ((row & 7) << 4);
        bf[n][kk] = *(const f16x8*)((const char*)Bs + tb);
      }
    }
    __builtin_amdgcn_s_setprio(1);
#pragma unroll
    for (int m = 0; m < 2; ++m)
#pragma unroll
      for (int n = 0; n < 4; ++n)
#pragma unroll
        for (int kk = 0; kk < 2; ++kk)
          acc[m][n] = __builtin_amdgcn_mfma_f32_16x16x32_f16(af[m][kk], bf[n][kk], acc[m][n], 0, 0, 0);
    __builtin_amdgcn_s_setprio(0);
    __syncthreads();
  }

  int rb = m0 + wr * 32;
  int cb = n0 + wc * 64;
#pragma unroll
  for (int m = 0; m < 2; ++m) {
    int row0 = rb + m * 16 + 4 * g;
#pragma unroll
    for (int n = 0; n < 4; ++n) {
      int col = cb + n * 16 + c;
      float bv = bias[col];
#pragma unroll
      for (int r = 0; r < 4; ++r) O[(size_t)(row0 + r) * N + col] = acc[m][n][r] + bv;
    }
  }
}

// ---------------- causal flash attention v7: kv-parity split + flash merge ----------------
// Block = 256 thr / 4 waves: wave (qh, par) = (w&1, w>>1). qh picks 32 q-rows of the
// 64-row chunk; par picks kv-tile parity. Each wave runs an independent online softmax
// over its parity's tiles (halves the serial tile chain of the longest block: 32 -> 16
// steps), then par1 publishes (m,l,O) to LDS and par0 does the exact flash combine.
// Grid 1024 = 32 slots x 32 bh, cb = 31-uu (big chunks dispatch first); LDS 64 KB ->
// 2 blocks/CU resident + 512 queued blocks backfill retiring CUs.
#define THR2 11.5f  // defer-max threshold, log2 domain
__global__ __launch_bounds__(256, 2) void attn_kernel(const f16* __restrict__ Q,
                                                      const f16* __restrict__ K,
                                                      const f16* __restrict__ VT,
                                                      f16* __restrict__ AO) {
  __shared__ __attribute__((aligned(16))) f16 Ksh[2][2][64 * 64];  // [buf][par] 32 KB
  __shared__ __attribute__((aligned(16))) f16 Vsh[2][2][64 * 64];  // 32 KB
  const int BUFO = 2 * 64 * 64;  // f16 elems between buf0/buf1
  int tid = threadIdx.x;
  int w = tid >> 6, lane = tid & 63;
  int c = lane & 31, hi = lane >> 5;
  int qh = w & 1, par = w >> 1;
  int blk = blockIdx.x;
  int bh = blk & 31;        // low bits -> head pinned per XCD
  int uu = blk >> 5;
  int cb = 31 - uu;         // big chunks first -> backfill-friendly schedule
  int b = bh >> 4, h = bh & 15;
  int q0 = cb * 64 + qh * 32;
  const int NT = cb + 1;
  const size_t brow = (size_t)b * SEQ;
  const int hcol = h * 64;

  // staging geometry: wave (qh,par) stages tile (t0+par), rows qh*32 + j*8 + (lane>>3)
  int sr = lane >> 3;
  int seo = ((lane & 7) ^ sr) << 3;
  const f16* Kgb = K + (size_t)(brow + qh * 32 + sr) * D_MODEL + hcol + seo;  // + kv*D_MODEL
  const f16* Vgb = VT + ((size_t)bh * 64 + qh * 32 + sr) * SEQ + seo;         // + kv
  f16* Kshf = &Ksh[0][0][0];
  f16* Vshf = &Vsh[0][0][0];
  f16* KshW = Kshf + par * 4096 + qh * 32 * 64;
  f16* VshW = Vshf + par * 4096 + qh * 32 * 64;

  // Q B-fragments (col=q-row=c, k = 16*kk + 8*hi + j), pre-scaled by log2e
  const f16 LOG2E = (f16)1.44269504f;
  f16x8 qf[4];
  const f16* Qp = Q + (size_t)(brow + q0 + c) * D_MODEL + hcol + 8 * hi;
#pragma unroll
  for (int kk = 0; kk < 4; ++kk) {
    qf[kk] = *(const f16x8*)(Qp + 16 * kk);
#pragma unroll
    for (int j = 0; j < 8; ++j) qf[kk][j] = (f16)(qf[kk][j] * LOG2E);
  }

  float m_st = -1e30f, l_st = 0.f;
  f32x16 o0 = {}, o1 = {};  // O^T accumulators, d-tiles 0..31 / 32..63; col=q per lane

  // prologue: stage pair {0,1} into buf 0 (this wave: tile par, if it exists)
  if (par < NT) {
    int kv = par * 64;
#pragma unroll
    for (int j = 0; j < 4; ++j) {
      gload_lds16(Kgb + (size_t)(kv + j * 8) * D_MODEL, KshW + (j * 8) * 64);
      gload_lds16(Vgb + (size_t)(j * 8) * SEQ + kv, VshW + (j * 8) * 64);
    }
  }
  __syncthreads();

  int rsw = (c & 7) << 4;
  int cur = 0;
  const int U = (NT + 1) >> 1;
  for (int u = 0; u < U; ++u) {
    int tpre = 2 * u + 2 + par;
    if (tpre < NT) {
      int kv = tpre * 64;
      f16* kd = KshW + (cur ^ 1) * BUFO;
      f16* vd = VshW + (cur ^ 1) * BUFO;
#pragma unroll
      for (int j = 0; j < 4; ++j) {
        gload_lds16(Kgb + (size_t)(kv + j * 8) * D_MODEL, kd + (j * 8) * 64);
        gload_lds16(Vgb + (size_t)(j * 8) * SEQ + kv, vd + (j * 8) * 64);
      }
    }
    int t = 2 * u + par;
    if (t < NT) {
      const char* Kb = (const char*)(Kshf + cur * BUFO + par * 4096);
      const char* Vb = (const char*)(Vshf + cur * BUFO + par * 4096);
      // ---- QK^T swapped: S^T[kv][q] = K . Q^T ----
      f16x8 kf[2][4];
#pragma unroll
      for (int ks = 0; ks < 2; ++ks)
#pragma unroll
        for (int kk = 0; kk < 4; ++kk)
          kf[ks][kk] = *(const f16x8*)(Kb + (((ks * 32 + c) * 128 + 32 * kk + 16 * hi) ^ rsw));
      f32x16 s0 = {}, s1 = {};
      __builtin_amdgcn_s_setprio(1);
#pragma unroll
      for (int kk = 0; kk < 4; ++kk) {
        s0 = __builtin_amdgcn_mfma_f32_32x32x16_f16(kf[0][kk], qf[kk], s0, 0, 0, 0);
        s1 = __builtin_amdgcn_mfma_f32_32x32x16_f16(kf[1][kk], qf[kk], s1, 0, 0, 0);
      }
      __builtin_amdgcn_s_setprio(0);
      // hoist V reads: independent of softmax, covers ds latency under VALU
      f16x8 vf[2][4];
#pragma unroll
      for (int dt = 0; dt < 2; ++dt)
#pragma unroll
        for (int kk = 0; kk < 4; ++kk)
          vf[dt][kk] = *(const f16x8*)(Vb + (((dt * 32 + c) * 128 + 32 * kk + 16 * hi) ^ rsw));
      // ---- causal mask (diagonal tile only); kv = 64t + 32ks + (r&3)+8(r>>2)+4hi ----
      if (t == NT - 1) {
        int q = q0 + c;
        int kvb = t * 64 + 4 * hi;
#pragma unroll
        for (int r = 0; r < 16; ++r) {
          int kv = kvb + (r & 3) + 8 * (r >> 2);
          if (kv > q) s0[r] = -1e30f;
          if (kv + 32 > q) s1[r] = -1e30f;
        }
      }
      // ---- online softmax: each lane holds 32 scores of ONE q-row (other half at lane^32) ----
      float t8[8];
#pragma unroll
      for (int r = 0; r < 8; ++r)
        t8[r] = fmaxf(fmaxf(s0[r], s0[r + 8]), fmaxf(s1[r], s1[r + 8]));
      float pm = fmaxf(fmaxf(fmaxf(t8[0], t8[1]), fmaxf(t8[2], t8[3])),
                       fmaxf(fmaxf(t8[4], t8[5]), fmaxf(t8[6], t8[7])));
      float mx = fmaxf(pm, __shfl_xor(pm, 32));
      if (__any(mx > m_st + THR2)) {
        float mnew = fmaxf(m_st, mx);
        float corr = __builtin_amdgcn_exp2f(m_st - mnew);
        l_st *= corr;
#pragma unroll
        for (int r = 0; r < 16; ++r) { o0[r] *= corr; o1[r] *= corr; }
        m_st = mnew;
      }
      float ts[16];
#pragma unroll
      for (int r = 0; r < 16; ++r) {
        float p0 = __builtin_amdgcn_exp2f(s0[r] - m_st);  // <= 2^11.5, f16-safe
        float p1 = __builtin_amdgcn_exp2f(s1[r] - m_st);
        s0[r] = p0; s1[r] = p1;
        ts[r] = p0 + p1;
      }
#pragma unroll
      for (int st = 8; st > 0; st >>= 1)
#pragma unroll
        for (int r = 0; r < st; ++r) ts[r] += ts[r + st];
      l_st += ts[0];
      // ---- P -> PV B-fragments in-register (cvt_pkrtz pairs + permlane32 hi/lo swap) ----
      union PU { unsigned int u[4]; f16x8 v; };
      PU pu[4];
#pragma unroll
      for (int kk = 0; kk < 4; ++kk) {
        int rb = 8 * (kk & 1);
        unsigned int la0, la1, lb0, lb1;
        if (kk < 2) {
          la0 = pkrtz(s0[rb + 0], s0[rb + 1]);
          la1 = pkrtz(s0[rb + 2], s0[rb + 3]);
          lb0 = pkrtz(s0[rb + 4], s0[rb + 5]);
          lb1 = pkrtz(s0[rb + 6], s0[rb + 7]);
        } else {
          la0 = pkrtz(s1[rb + 0], s1[rb + 1]);
          la1 = pkrtz(s1[rb + 2], s1[rb + 3]);
          lb0 = pkrtz(s1[rb + 4], s1[rb + 5]);
          lb1 = pkrtz(s1[rb + 6], s1[rb + 7]);
        }
        asm("v_permlane32_swap_b32 %0, %1" : "+v"(la0), "+v"(lb0));
        asm("v_permlane32_swap_b32 %0, %1" : "+v"(la1), "+v"(lb1));
        pu[kk].u[0] = la0; pu[kk].u[1] = la1; pu[kk].u[2] = lb0; pu[kk].u[3] = lb1;
      }
      // ---- PV: O^T[d][q] += V^T[d][kv] * P^T[kv][q] ----
      __builtin_amdgcn_s_setprio(1);
#pragma unroll
      for (int kk = 0; kk < 4; ++kk) {
        o0 = __builtin_amdgcn_mfma_f32_32x32x16_f16(vf[0][kk], pu[kk].v, o0, 0, 0, 0);
        o1 = __builtin_amdgcn_mfma_f32_32x32x16_f16(vf[1][kk], pu[kk].v, o1, 0, 0, 0);
      }
      __builtin_amdgcn_s_setprio(0);
    }
    __syncthreads();
    cur ^= 1;
  }

  // ---- flash merge of parity partials (exact): par1 publishes, par0 combines ----
  float* sc = (float*)Kshf;  // K LDS dead after loop; 128 x 34 f32 = 17 KB
  int mb = (qh * 64 + lane) * 34;
  if (par == 1) {
    sc[mb] = m_st;
    sc[mb + 1] = l_st;
#pragma unroll
    for (int r = 0; r < 16; ++r) { sc[mb + 2 + r] = o0[r]; sc[mb + 18 + r] = o1[r]; }
  }
  __syncthreads();
  if (par == 0) {
    float m1 = sc[mb], l1 = sc[mb + 1];
    float mm = fmaxf(m_st, m1);
    float c0 = __builtin_amdgcn_exp2f(m_st - mm);
    float c1 = __builtin_amdgcn_exp2f(m1 - mm);
    float l = l_st * c0 + l1 * c1;
#pragma unroll
    for (int r = 0; r < 16; ++r) {
      o0[r] = o0[r] * c0 + sc[mb + 2 + r] * c1;
      o1[r] = o1[r] * c0 + sc[mb + 18 + r] * c1;
    }
    // combine hi/lo kv-half row sums, normalize, write AO[bh][s][64]
    float lt = l + __shfl_xor(l, 32);
    float linv = 1.0f / lt;
    f16* aoq = AO + ((size_t)bh * SEQ + q0 + c) * 64 + 4 * hi;
#pragma unroll
    for (int rq = 0; rq < 4; ++rq) {
      f16x4 h0, h1;
#pragma unroll
      for (int r = 0; r < 4; ++r) {
        h0[r] = (f16)(o0[4 * rq + r] * linv);
        h1[r] = (f16)(o1[4 * rq + r] * linv);
      }
      *(f16x4*)(aoq + 8 * rq) = h0;
      *(f16x4*)(aoq + 32 + 8 * rq) = h1;
    }
  }
}

extern "C" void kernel_launch(void* const* d_in, const int* in_sizes, int n_in,
                              void* d_out, int out_size, void* d_ws, size_t ws_size,
                              hipStream_t stream) {
  const float* q  = (const float*)d_in[0];
  const float* k  = (const float*)d_in[1];
  const float* v  = (const float*)d_in[2];
  const float* wq = (const float*)d_in[3];
  const float* bq = (const float*)d_in[4];
  const float* wk = (const float*)d_in[5];
  const float* bk = (const float*)d_in[6];
  const float* wv = (const float*)d_in[7];
  const float* bv = (const float*)d_in[8];
  const float* wo = (const float*)d_in[9];
  const float* bo = (const float*)d_in[10];

  const size_t TEN = (size_t)MTOT * D_MODEL;
  const size_t WEL = (size_t)D_MODEL * D_MODEL;
  f16* ws  = (f16*)d_ws;
  f16* q16 = ws;
  f16* k16 = q16 + TEN;
  f16* v16 = k16 + TEN;
  f16* wT  = v16 + TEN;
  f16* Q16 = wT + 4 * WEL;
  f16* K16 = Q16 + TEN;
  f16* VT16 = K16 + TEN;
  f16* AO  = q16;  // alias: q16 dead after QKV projection

  cvt_all<<<7168, 256, 0, stream>>>(q, k, v, wq, wk, wv, wo, q16, wT);
  gemm_qkv<<<dim3(32, 8, 3), 256, 0, stream>>>(q16, k16, v16, wT, bq, bk, bv, Q16, K16, VT16);
  attn_kernel<<<1024, 256, 0, stream>>>(Q16, K16, VT16, AO);
  gemm_out<<<dim3(64, 8), 256, 0, stream>>>(AO, wT + 3 * WEL, bo, (float*)d_out);
}

// Round 3
// 107.298 us; speedup vs baseline: 1.1497x; 1.0324x over previous
//
#include <hip/hip_runtime.h>

typedef __fp16 f16;
typedef __fp16 f16x8 __attribute__((ext_vector_type(8)));
typedef __fp16 f16x4 __attribute__((ext_vector_type(4)));
typedef __fp16 f16x2 __attribute__((ext_vector_type(2)));
typedef float f32x4 __attribute__((ext_vector_type(4)));
typedef float f32x16 __attribute__((ext_vector_type(16)));

#define D_MODEL 1024
#define SEQ 2048
#define NH 16
#define MTOT 4096  // B*S

typedef const __attribute__((address_space(1))) unsigned int* gp1_t;
typedef __attribute__((address_space(3))) unsigned int* lp3_t;

__device__ __forceinline__ void gload_lds16(const void* g, void* l) {
  __builtin_amdgcn_global_load_lds((gp1_t)g, (lp3_t)l, 16, 0, 0);
}

// Z-row r' -> AO superrow j (the reference's transpose/view bug, closed form)
__device__ __forceinline__ int permrow(int r) {
  int bp = r >> 11, u = (r >> 7) & 15, t = r & 127;
  int g16 = (bp << 4) | u;
  return ((((g16 & 1) << 4) | (g16 >> 1)) << 7) + t;  // (b*16+h)*128 + t
}

__device__ __forceinline__ unsigned int pkrtz(float a, float b) {
  union { f16x2 h; unsigned int u; } z;
  z.h = __builtin_amdgcn_cvt_pkrtz(a, b);
  return z.u;
}

// ---------------- merged converts: qkv fp32->f16 (blocks 0..6143), wT (blocks 6144..7167) ----------------
__global__ __launch_bounds__(256) void cvt_all(const float* __restrict__ q,
                                               const float* __restrict__ k,
                                               const float* __restrict__ v,
                                               const float* __restrict__ wq,
                                               const float* __restrict__ wk,
                                               const float* __restrict__ wv,
                                               const float* __restrict__ wo,
                                               f16* __restrict__ qkv16,
                                               f16* __restrict__ wT) {
  __shared__ float tl[64][65];
  int bid = blockIdx.x, tid = threadIdx.x;
  if (bid < 6144) {
    int i = bid * 256 + tid;
    const int NT = (MTOT * D_MODEL) / 8;
    const float* src;
    int t;
    if (i < NT) { src = q; t = i; }
    else if (i < 2 * NT) { src = k; t = i - NT; }
    else { src = v; t = i - 2 * NT; }
    const float4* s4 = (const float4*)src;
    float4 a = s4[2 * t], b = s4[2 * t + 1];
    f16x8 h;
    h[0] = (f16)a.x; h[1] = (f16)a.y; h[2] = (f16)a.z; h[3] = (f16)a.w;
    h[4] = (f16)b.x; h[5] = (f16)b.y; h[6] = (f16)b.z; h[7] = (f16)b.w;
    *(f16x8*)(qkv16 + (size_t)i * 8) = h;
  } else {
    int bb = bid - 6144;
    int mat = bb >> 8, tile = bb & 255;
    int tk = (tile >> 4) << 6, tn = (tile & 15) << 6;
    const float* W = mat == 0 ? wq : mat == 1 ? wk : mat == 2 ? wv : wo;
    int rr = tid >> 4, c4 = (tid & 15) << 2;
#pragma unroll
    for (int it = 0; it < 4; ++it) {
      const float* p = W + (size_t)(tk + it * 16 + rr) * D_MODEL + tn + c4;
      float4 val = *(const float4*)p;
      tl[it * 16 + rr][c4 + 0] = val.x;
      tl[it * 16 + rr][c4 + 1] = val.y;
      tl[it * 16 + rr][c4 + 2] = val.z;
      tl[it * 16 + rr][c4 + 3] = val.w;
    }
    __syncthreads();
    int n = tid & 63, kseg = (tid >> 6) << 4;
    f16x8 lo, hi;
#pragma unroll
    for (int j = 0; j < 8; ++j) lo[j] = (f16)tl[kseg + j][n];
#pragma unroll
    for (int j = 0; j < 8; ++j) hi[j] = (f16)tl[kseg + 8 + j][n];
    f16* d = wT + (size_t)mat * (D_MODEL * D_MODEL) + (size_t)(tn + n) * D_MODEL + tk + kseg;
    *(f16x8*)d = lo;
    *(f16x8*)(d + 8) = hi;
  }
}

// ---------------- fused QKV projection GEMM v2: 256x256 tiles, 8 waves, 4-phase pipeline ----------------
// Per K-tile (BK=64): 4 quadrant phases, each {ds_read subtile frags | issue 2/8 next-tile
// global_load_lds -> raw s_barrier (loads stay in flight) -> setprio+16 MFMA}. One full
// __syncthreads (vmcnt drain) per tile boundary; next-tile loads were issued 1-4 phases
// earlier so the drain is short. LDS 128 KiB dynamic (dbuf A+B), 1 block/CU, grid (16,4,3).
#define QTILE (256 * 64)
__global__ __launch_bounds__(512, 2) void gemm_qkv(const f16* __restrict__ q16,
                                                   const f16* __restrict__ k16,
                                                   const f16* __restrict__ v16,
                                                   const f16* __restrict__ wT,
                                                   const float* __restrict__ bq,
                                                   const float* __restrict__ bk,
                                                   const float* __restrict__ bv,
                                                   f16* __restrict__ Q16,
                                                   f16* __restrict__ K16,
                                                   f16* __restrict__ VT16) {
  extern __shared__ __attribute__((aligned(16))) f16 sm[];  // [buf][mat][256*64]
  const int K = D_MODEL, N = D_MODEL;
  const size_t WEL = (size_t)D_MODEL * D_MODEL;
  int z = blockIdx.z;
  const f16* A = z == 0 ? q16 : z == 1 ? k16 : v16;
  const f16* BT = wT + (size_t)z * WEL;
  const float* bias = z == 0 ? bq : z == 1 ? bk : bv;

  int tid = threadIdx.x;
  int w = tid >> 6, lane = tid & 63;
  int g = lane >> 4, c = lane & 15;
  int wr = w >> 2, wc = w & 3;
  int m0 = blockIdx.x * 256, n0 = blockIdx.y * 256;
  f32x4 acc[8][4] = {};

  // staging geometry (verified pattern): wave w, instr j stages rows w*32+j*8+(lane>>3)
  int sr = lane >> 3;
  int sc8 = ((lane & 7) ^ sr) << 3;  // pre-swizzled col element offset
  const f16* Ag = A + (size_t)(m0 + w * 32 + sr) * K + sc8;
  const f16* Bg = BT + (size_t)(n0 + w * 32 + sr) * K + sc8;

  // prologue: stage tile 0 into buf0
  {
    f16* A0 = sm;
    f16* B0 = sm + QTILE;
#pragma unroll
    for (int j = 0; j < 4; ++j) {
      gload_lds16(Ag + (size_t)(j * 8) * K, A0 + (w * 32 + j * 8) * 64);
      gload_lds16(Bg + (size_t)(j * 8) * K, B0 + (w * 32 + j * 8) * 64);
    }
  }
  __syncthreads();

  const int NKT = K / 64;
  for (int t = 0; t < NKT; ++t) {
    const char* Ac = (const char*)(sm + (t & 1) * 2 * QTILE);
    const char* Bc = Ac + QTILE * 2;  // bytes
    f16* An = sm + ((t + 1) & 1) * 2 * QTILE;
    f16* Bn = An + QTILE;
    const f16* Agt = Ag + (t + 1) * 64;
    const f16* Bgt = Bg + (t + 1) * 64;
    bool pre = (t + 1 < NKT);

    f16x8 af[4][2], bf[2][2];
    // ======== phase 0: quadrant (qm=0, qn=0) ========
#pragma unroll
    for (int mi = 0; mi < 4; ++mi)
#pragma unroll
      for (int kk = 0; kk < 2; ++kk) {
        int row = wr * 128 + mi * 16 + c;
        af[mi][kk] = *(const f16x8*)(Ac + ((row * 128 + kk * 64 + g * 16) ^ ((row & 7) << 4)));
      }
#pragma unroll
    for (int ni = 0; ni < 2; ++ni)
#pragma unroll
      for (int kk = 0; kk < 2; ++kk) {
        int row = wc * 64 + ni * 16 + c;
        bf[ni][kk] = *(const f16x8*)(Bc + ((row * 128 + kk * 64 + g * 16) ^ ((row & 7) << 4)));
      }
    if (pre) {
      gload_lds16(Agt, An + (w * 32) * 64);
      gload_lds16(Agt + (size_t)(8) * K, An + (w * 32 + 8) * 64);
    }
    __builtin_amdgcn_s_barrier();
    __builtin_amdgcn_s_setprio(1);
#pragma unroll
    for (int mi = 0; mi < 4; ++mi)
#pragma unroll
      for (int ni = 0; ni < 2; ++ni)
#pragma unroll
        for (int kk = 0; kk < 2; ++kk)
          acc[mi][ni] = __builtin_amdgcn_mfma_f32_16x16x32_f16(af[mi][kk], bf[ni][kk], acc[mi][ni], 0, 0, 0);
    __builtin_amdgcn_s_setprio(0);
    // ======== phase 1: quadrant (qm=0, qn=1): new bf (n=2,3), reuse af ========
#pragma unroll
    for (int ni = 0; ni < 2; ++ni)
#pragma unroll
      for (int kk = 0; kk < 2; ++kk) {
        int row = wc * 64 + (2 + ni) * 16 + c;
        bf[ni][kk] = *(const f16x8*)(Bc + ((row * 128 + kk * 64 + g * 16) ^ ((row & 7) << 4)));
      }
    if (pre) {
      gload_lds16(Agt + (size_t)(16) * K, An + (w * 32 + 16) * 64);
      gload_lds16(Agt + (size_t)(24) * K, An + (w * 32 + 24) * 64);
    }
    __builtin_amdgcn_s_barrier();
    __builtin_amdgcn_s_setprio(1);
#pragma unroll
    for (int mi = 0; mi < 4; ++mi)
#pragma unroll
      for (int ni = 0; ni < 2; ++ni)
#pragma unroll
        for (int kk = 0; kk < 2; ++kk)
          acc[mi][2 + ni] = __builtin_amdgcn_mfma_f32_16x16x32_f16(af[mi][kk], bf[ni][kk], acc[mi][2 + ni], 0, 0, 0);
    __builtin_amdgcn_s_setprio(0);
    // ======== phase 2: quadrant (qm=1, qn=1): new af (m=4..7), reuse bf ========
#pragma unroll
    for (int mi = 0; mi < 4; ++mi)
#pragma unroll
      for (int kk = 0; kk < 2; ++kk) {
        int row = wr * 128 + 64 + mi * 16 + c;
        af[mi][kk] = *(const f16x8*)(Ac + ((row * 128 + kk * 64 + g * 16) ^ ((row & 7) << 4)));
      }
    if (pre) {
      gload_lds16(Bgt, Bn + (w * 32) * 64);
      gload_lds16(Bgt + (size_t)(8) * K, Bn + (w * 32 + 8) * 64);
    }
    __builtin_amdgcn_s_barrier();
    __builtin_amdgcn_s_setprio(1);
#pragma unroll
    for (int mi = 0; mi < 4; ++mi)
#pragma unroll
      for (int ni = 0; ni < 2; ++ni)
#pragma unroll
        for (int kk = 0; kk < 2; ++kk)
          acc[4 + mi][2 + ni] = __builtin_amdgcn_mfma_f32_16x16x32_f16(af[mi][kk], bf[ni][kk], acc[4 + mi][2 + ni], 0, 0, 0);
    __builtin_amdgcn_s_setprio(0);
    // ======== phase 3: quadrant (qm=1, qn=0): re-read bf (n=0,1), reuse af ========
#pragma unroll
    for (int ni = 0; ni < 2; ++ni)
#pragma unroll
      for (int kk = 0; kk < 2; ++kk) {
        int row = wc * 64 + ni * 16 + c;
        bf[ni][kk] = *(const f16x8*)(Bc + ((row * 128 + kk * 64 + g * 16) ^ ((row & 7) << 4)));
      }
    if (pre) {
      gload_lds16(Bgt + (size_t)(16) * K, Bn + (w * 32 + 16) * 64);
      gload_lds16(Bgt + (size_t)(24) * K, Bn + (w * 32 + 24) * 64);
    }
    __builtin_amdgcn_s_barrier();
    __builtin_amdgcn_s_setprio(1);
#pragma unroll
    for (int mi = 0; mi < 4; ++mi)
#pragma unroll
      for (int ni = 0; ni < 2; ++ni)
#pragma unroll
        for (int kk = 0; kk < 2; ++kk)
          acc[4 + mi][ni] = __builtin_amdgcn_mfma_f32_16x16x32_f16(af[mi][kk], bf[ni][kk], acc[4 + mi][ni], 0, 0, 0);
    __builtin_amdgcn_s_setprio(0);
    __syncthreads();  // drains vmcnt: next tile fully resident
  }

  int rb = m0 + wr * 128;
  int cb = n0 + wc * 64;
  if (z < 2) {
    f16* O = z == 0 ? Q16 : K16;
#pragma unroll
    for (int m = 0; m < 8; ++m) {
      int row0 = rb + m * 16 + 4 * g;
#pragma unroll
      for (int n = 0; n < 4; ++n) {
        int col = cb + n * 16 + c;
        float bv2 = bias[col];
#pragma unroll
        for (int r = 0; r < 4; ++r) O[(size_t)(row0 + r) * N + col] = (f16)(acc[m][n][r] + bv2);
      }
    }
  } else {
    f16* O = VT16;
#pragma unroll
    for (int m = 0; m < 8; ++m) {
      int s0f = rb + m * 16 + 4 * g;
      int bb = s0f >> 11, s = s0f & (SEQ - 1);
#pragma unroll
      for (int n = 0; n < 4; ++n) {
        int col = cb + n * 16 + c;
        float bv2 = bias[col];
        f16x4 hv;
#pragma unroll
        for (int r = 0; r < 4; ++r) hv[r] = (f16)(acc[m][n][r] + bv2);
        *(f16x4*)(O + ((size_t)(bb * NH + (col >> 6)) * 64 + (col & 63)) * SEQ + s) = hv;
      }
    }
  }
}

// ---------------- O-projection GEMM: 64x128 tiles, permuted A rows, f32 out ----------------
__global__ __launch_bounds__(256, 2) void gemm_out(const f16* __restrict__ A,
                                                   const f16* __restrict__ BT,
                                                   const float* __restrict__ bias,
                                                   float* __restrict__ O) {
  const int K = D_MODEL, N = D_MODEL;
  __shared__ f16 As[64 * 64];
  __shared__ f16 Bs[128 * 64];
  int tid = threadIdx.x;
  int w = tid >> 6, lane = tid & 63;
  int g = lane >> 4, c = lane & 15;
  int wr = w >> 1, wc = w & 1;
  int m0 = blockIdx.x * 64, n0 = blockIdx.y * 128;
  f32x4 acc[2][4] = {};

  for (int kt = 0; kt < K; kt += 64) {
#pragma unroll
    for (int i = 0; i < 2; ++i) {
      int seg = w * 2 + i;
      int p = seg * 1024 + lane * 16;
      int row = p >> 7;
      int colb = (p & 127) ^ ((row & 7) << 4);
      int ae = kt + (colb >> 1);
      gload_lds16(A + (size_t)permrow(m0 + row) * K + ae, &As[seg * 512]);
    }
#pragma unroll
    for (int i = 0; i < 4; ++i) {
      int seg = w * 4 + i;
      int p = seg * 1024 + lane * 16;
      int row = p >> 7;
      int colb = (p & 127) ^ ((row & 7) << 4);
      int ae = kt + (colb >> 1);
      gload_lds16(BT + (size_t)(n0 + row) * K + ae, &Bs[seg * 512]);
    }
    __syncthreads();
    f16x8 af[2][2], bf[4][2];
#pragma unroll
    for (int m = 0; m < 2; ++m) {
#pragma unroll
      for (int kk = 0; kk < 2; ++kk) {
        int row = wr * 32 + m * 16 + c;
        int tb = (row * 128 + kk * 64 + g * 16) ^ ((row & 7) << 4);
        af[m][kk] = *(const f16x8*)((const char*)As + tb);
      }
    }
#pragma unroll
    for (int n = 0; n < 4; ++n) {
#pragma unroll
      for (int kk = 0; kk < 2; ++kk) {
        int row = wc * 64 + n * 16 + c;
        int tb = (row * 128 + kk * 64 + g * 16) ^ ((row & 7) << 4);
        bf[n][kk] = *(const f16x8*)((const char*)Bs + tb);
      }
    }
    __builtin_amdgcn_s_setprio(1);
#pragma unroll
    for (int m = 0; m < 2; ++m)
#pragma unroll
      for (int n = 0; n < 4; ++n)
#pragma unroll
        for (int kk = 0; kk < 2; ++kk)
          acc[m][n] = __builtin_amdgcn_mfma_f32_16x16x32_f16(af[m][kk], bf[n][kk], acc[m][n], 0, 0, 0);
    __builtin_amdgcn_s_setprio(0);
    __syncthreads();
  }

  int rb = m0 + wr * 32;
  int cb = n0 + wc * 64;
#pragma unroll
  for (int m = 0; m < 2; ++m) {
    int row0 = rb + m * 16 + 4 * g;
#pragma unroll
    for (int n = 0; n < 4; ++n) {
      int col = cb + n * 16 + c;
      float bv = bias[col];
#pragma unroll
      for (int r = 0; r < 4; ++r) O[(size_t)(row0 + r) * N + col] = acc[m][n][r] + bv;
    }
  }
}

// ---------------- causal flash attention v7: kv-parity split + flash merge ----------------
#define THR2 11.5f  // defer-max threshold, log2 domain
__global__ __launch_bounds__(256, 2) void attn_kernel(const f16* __restrict__ Q,
                                                      const f16* __restrict__ K,
                                                      const f16* __restrict__ VT,
                                                      f16* __restrict__ AO) {
  __shared__ __attribute__((aligned(16))) f16 Ksh[2][2][64 * 64];  // [buf][par] 32 KB
  __shared__ __attribute__((aligned(16))) f16 Vsh[2][2][64 * 64];  // 32 KB
  const int BUFO = 2 * 64 * 64;  // f16 elems between buf0/buf1
  int tid = threadIdx.x;
  int w = tid >> 6, lane = tid & 63;
  int c = lane & 31, hi = lane >> 5;
  int qh = w & 1, par = w >> 1;
  int blk = blockIdx.x;
  int bh = blk & 31;        // low bits -> head pinned per XCD
  int uu = blk >> 5;
  int cb = 31 - uu;         // big chunks first -> backfill-friendly schedule
  int b = bh >> 4, h = bh & 15;
  int q0 = cb * 64 + qh * 32;
  const int NT = cb + 1;
  const size_t brow = (size_t)b * SEQ;
  const int hcol = h * 64;

  // staging geometry: wave (qh,par) stages tile (t0+par), rows qh*32 + j*8 + (lane>>3)
  int sr = lane >> 3;
  int seo = ((lane & 7) ^ sr) << 3;
  const f16* Kgb = K + (size_t)(brow + qh * 32 + sr) * D_MODEL + hcol + seo;  // + kv*D_MODEL
  const f16* Vgb = VT + ((size_t)bh * 64 + qh * 32 + sr) * SEQ + seo;         // + kv
  f16* Kshf = &Ksh[0][0][0];
  f16* Vshf = &Vsh[0][0][0];
  f16* KshW = Kshf + par * 4096 + qh * 32 * 64;
  f16* VshW = Vshf + par * 4096 + qh * 32 * 64;

  // Q B-fragments (col=q-row=c, k = 16*kk + 8*hi + j), pre-scaled by log2e
  const f16 LOG2E = (f16)1.44269504f;
  f16x8 qf[4];
  const f16* Qp = Q + (size_t)(brow + q0 + c) * D_MODEL + hcol + 8 * hi;
#pragma unroll
  for (int kk = 0; kk < 4; ++kk) {
    qf[kk] = *(const f16x8*)(Qp + 16 * kk);
#pragma unroll
    for (int j = 0; j < 8; ++j) qf[kk][j] = (f16)(qf[kk][j] * LOG2E);
  }

  float m_st = -1e30f, l_st = 0.f;
  f32x16 o0 = {}, o1 = {};  // O^T accumulators, d-tiles 0..31 / 32..63; col=q per lane

  // prologue: stage pair {0,1} into buf 0 (this wave: tile par, if it exists)
  if (par < NT) {
    int kv = par * 64;
#pragma unroll
    for (int j = 0; j < 4; ++j) {
      gload_lds16(Kgb + (size_t)(kv + j * 8) * D_MODEL, KshW + (j * 8) * 64);
      gload_lds16(Vgb + (size_t)(j * 8) * SEQ + kv, VshW + (j * 8) * 64);
    }
  }
  __syncthreads();

  int rsw = (c & 7) << 4;
  int cur = 0;
  const int U = (NT + 1) >> 1;
  for (int u = 0; u < U; ++u) {
    int tpre = 2 * u + 2 + par;
    if (tpre < NT) {
      int kv = tpre * 64;
      f16* kd = KshW + (cur ^ 1) * BUFO;
      f16* vd = VshW + (cur ^ 1) * BUFO;
#pragma unroll
      for (int j = 0; j < 4; ++j) {
        gload_lds16(Kgb + (size_t)(kv + j * 8) * D_MODEL, kd + (j * 8) * 64);
        gload_lds16(Vgb + (size_t)(j * 8) * SEQ + kv, vd + (j * 8) * 64);
      }
    }
    int t = 2 * u + par;
    if (t < NT) {
      const char* Kb = (const char*)(Kshf + cur * BUFO + par * 4096);
      const char* Vb = (const char*)(Vshf + cur * BUFO + par * 4096);
      // ---- QK^T swapped: S^T[kv][q] = K . Q^T ----
      f16x8 kf[2][4];
#pragma unroll
      for (int ks = 0; ks < 2; ++ks)
#pragma unroll
        for (int kk = 0; kk < 4; ++kk)
          kf[ks][kk] = *(const f16x8*)(Kb + (((ks * 32 + c) * 128 + 32 * kk + 16 * hi) ^ rsw));
      f32x16 s0 = {}, s1 = {};
      __builtin_amdgcn_s_setprio(1);
#pragma unroll
      for (int kk = 0; kk < 4; ++kk) {
        s0 = __builtin_amdgcn_mfma_f32_32x32x16_f16(kf[0][kk], qf[kk], s0, 0, 0, 0);
        s1 = __builtin_amdgcn_mfma_f32_32x32x16_f16(kf[1][kk], qf[kk], s1, 0, 0, 0);
      }
      __builtin_amdgcn_s_setprio(0);
      // hoist V reads: independent of softmax, covers ds latency under VALU
      f16x8 vf[2][4];
#pragma unroll
      for (int dt = 0; dt < 2; ++dt)
#pragma unroll
        for (int kk = 0; kk < 4; ++kk)
          vf[dt][kk] = *(const f16x8*)(Vb + (((dt * 32 + c) * 128 + 32 * kk + 16 * hi) ^ rsw));
      // ---- causal mask (diagonal tile only); kv = 64t + 32ks + (r&3)+8(r>>2)+4hi ----
      if (t == NT - 1) {
        int q = q0 + c;
        int kvb = t * 64 + 4 * hi;
#pragma unroll
        for (int r = 0; r < 16; ++r) {
          int kv = kvb + (r & 3) + 8 * (r >> 2);
          if (kv > q) s0[r] = -1e30f;
          if (kv + 32 > q) s1[r] = -1e30f;
        }
      }
      // ---- online softmax: each lane holds 32 scores of ONE q-row (other half at lane^32) ----
      float t8[8];
#pragma unroll
      for (int r = 0; r < 8; ++r)
        t8[r] = fmaxf(fmaxf(s0[r], s0[r + 8]), fmaxf(s1[r], s1[r + 8]));
      float pm = fmaxf(fmaxf(fmaxf(t8[0], t8[1]), fmaxf(t8[2], t8[3])),
                       fmaxf(fmaxf(t8[4], t8[5]), fmaxf(t8[6], t8[7])));
      float mx = fmaxf(pm, __shfl_xor(pm, 32));
      if (__any(mx > m_st + THR2)) {
        float mnew = fmaxf(m_st, mx);
        float corr = __builtin_amdgcn_exp2f(m_st - mnew);
        l_st *= corr;
#pragma unroll
        for (int r = 0; r < 16; ++r) { o0[r] *= corr; o1[r] *= corr; }
        m_st = mnew;
      }
      float ts[16];
#pragma unroll
      for (int r = 0; r < 16; ++r) {
        float p0 = __builtin_amdgcn_exp2f(s0[r] - m_st);  // <= 2^11.5, f16-safe
        float p1 = __builtin_amdgcn_exp2f(s1[r] - m_st);
        s0[r] = p0; s1[r] = p1;
        ts[r] = p0 + p1;
      }
#pragma unroll
      for (int st = 8; st > 0; st >>= 1)
#pragma unroll
        for (int r = 0; r < st; ++r) ts[r] += ts[r + st];
      l_st += ts[0];
      // ---- P -> PV B-fragments in-register (cvt_pkrtz pairs + permlane32 hi/lo swap) ----
      union PU { unsigned int u[4]; f16x8 v; };
      PU pu[4];
#pragma unroll
      for (int kk = 0; kk < 4; ++kk) {
        int rb = 8 * (kk & 1);
        unsigned int la0, la1, lb0, lb1;
        if (kk < 2) {
          la0 = pkrtz(s0[rb + 0], s0[rb + 1]);
          la1 = pkrtz(s0[rb + 2], s0[rb + 3]);
          lb0 = pkrtz(s0[rb + 4], s0[rb + 5]);
          lb1 = pkrtz(s0[rb + 6], s0[rb + 7]);
        } else {
          la0 = pkrtz(s1[rb + 0], s1[rb + 1]);
          la1 = pkrtz(s1[rb + 2], s1[rb + 3]);
          lb0 = pkrtz(s1[rb + 4], s1[rb + 5]);
          lb1 = pkrtz(s1[rb + 6], s1[rb + 7]);
        }
        asm("v_permlane32_swap_b32 %0, %1" : "+v"(la0), "+v"(lb0));
        asm("v_permlane32_swap_b32 %0, %1" : "+v"(la1), "+v"(lb1));
        pu[kk].u[0] = la0; pu[kk].u[1] = la1; pu[kk].u[2] = lb0; pu[kk].u[3] = lb1;
      }
      // ---- PV: O^T[d][q] += V^T[d][kv] * P^T[kv][q] ----
      __builtin_amdgcn_s_setprio(1);
#pragma unroll
      for (int kk = 0; kk < 4; ++kk) {
        o0 = __builtin_amdgcn_mfma_f32_32x32x16_f16(vf[0][kk], pu[kk].v, o0, 0, 0, 0);
        o1 = __builtin_amdgcn_mfma_f32_32x32x16_f16(vf[1][kk], pu[kk].v, o1, 0, 0, 0);
      }
      __builtin_amdgcn_s_setprio(0);
    }
    __syncthreads();
    cur ^= 1;
  }

  // ---- flash merge of parity partials (exact): par1 publishes, par0 combines ----
  float* sc = (float*)Kshf;  // K LDS dead after loop; 128 x 34 f32 = 17 KB
  int mb = (qh * 64 + lane) * 34;
  if (par == 1) {
    sc[mb] = m_st;
    sc[mb + 1] = l_st;
#pragma unroll
    for (int r = 0; r < 16; ++r) { sc[mb + 2 + r] = o0[r]; sc[mb + 18 + r] = o1[r]; }
  }
  __syncthreads();
  if (par == 0) {
    float m1 = sc[mb], l1 = sc[mb + 1];
    float mm = fmaxf(m_st, m1);
    float c0 = __builtin_amdgcn_exp2f(m_st - mm);
    float c1 = __builtin_amdgcn_exp2f(m1 - mm);
    float l = l_st * c0 + l1 * c1;
#pragma unroll
    for (int r = 0; r < 16; ++r) {
      o0[r] = o0[r] * c0 + sc[mb + 2 + r] * c1;
      o1[r] = o1[r] * c0 + sc[mb + 18 + r] * c1;
    }
    // combine hi/lo kv-half row sums, normalize, write AO[bh][s][64]
    float lt = l + __shfl_xor(l, 32);
    float linv = 1.0f / lt;
    f16* aoq = AO + ((size_t)bh * SEQ + q0 + c) * 64 + 4 * hi;
#pragma unroll
    for (int rq = 0; rq < 4; ++rq) {
      f16x4 h0, h1;
#pragma unroll
      for (int r = 0; r < 4; ++r) {
        h0[r] = (f16)(o0[4 * rq + r] * linv);
        h1[r] = (f16)(o1[4 * rq + r] * linv);
      }
      *(f16x4*)(aoq + 8 * rq) = h0;
      *(f16x4*)(aoq + 32 + 8 * rq) = h1;
    }
  }
}

extern "C" void kernel_launch(void* const* d_in, const int* in_sizes, int n_in,
                              void* d_out, int out_size, void* d_ws, size_t ws_size,
                              hipStream_t stream) {
  const float* q  = (const float*)d_in[0];
  const float* k  = (const float*)d_in[1];
  const float* v  = (const float*)d_in[2];
  const float* wq = (const float*)d_in[3];
  const float* bq = (const float*)d_in[4];
  const float* wk = (const float*)d_in[5];
  const float* bk = (const float*)d_in[6];
  const float* wv = (const float*)d_in[7];
  const float* bv = (const float*)d_in[8];
  const float* wo = (const float*)d_in[9];
  const float* bo = (const float*)d_in[10];

  const size_t TEN = (size_t)MTOT * D_MODEL;
  const size_t WEL = (size_t)D_MODEL * D_MODEL;
  f16* ws  = (f16*)d_ws;
  f16* q16 = ws;
  f16* k16 = q16 + TEN;
  f16* v16 = k16 + TEN;
  f16* wT  = v16 + TEN;
  f16* Q16 = wT + 4 * WEL;
  f16* K16 = Q16 + TEN;
  f16* VT16 = K16 + TEN;
  f16* AO  = q16;  // alias: q16 dead after QKV projection

  static bool attr_set = false;
  if (!attr_set) {
    hipFuncSetAttribute(reinterpret_cast<const void*>(&gemm_qkv),
                        hipFuncAttributeMaxDynamicSharedMemorySize, 131072);
    attr_set = true;
  }

  cvt_all<<<7168, 256, 0, stream>>>(q, k, v, wq, wk, wv, wo, q16, wT);
  gemm_qkv<<<dim3(16, 4, 3), 512, 131072, stream>>>(q16, k16, v16, wT, bq, bk, bv, Q16, K16, VT16);
  attn_kernel<<<1024, 256, 0, stream>>>(Q16, K16, VT16, AO);
  gemm_out<<<dim3(64, 8), 256, 0, stream>>>(AO, wT + 3 * WEL, bo, (float*)d_out);
}